// Round 4
// baseline (574.908 us; speedup 1.0000x reference)
//
#include <hip/hip_runtime.h>

typedef unsigned int u32;
typedef unsigned short u16;
typedef __bf16 bf16x8 __attribute__((ext_vector_type(8)));
typedef float f32x16 __attribute__((ext_vector_type(16)));

// ---------- helpers ----------
__device__ __forceinline__ u16 f2bf(float f) {
  u32 u = __float_as_uint(f);
  u32 r = (u + 0x7FFFu + ((u >> 16) & 1u)) >> 16;
  return (u16)r;
}

__device__ __forceinline__ u32 pack2bf(float h0, float h1) {
  return (u32)f2bf(h0) | ((u32)f2bf(h1) << 16);
}

__device__ __forceinline__ float fast_tanh(float x) {
  float e = __expf(2.0f * x);
  return 1.0f - 2.0f * __builtin_amdgcn_rcpf(e + 1.0f);
}

// bilinear interp matching jnp.searchsorted(side='right')-1 with clamping
__device__ __forceinline__ float inter2d_d(const float* xs, const float* ys,
                                           const float* tb, float xq, float yq) {
  xq = fminf(fmaxf(xq, xs[0]), xs[8]);
  yq = fminf(fmaxf(yq, ys[0]), ys[13]);
  int i = 0, j = 0;
#pragma unroll
  for (int k = 1; k <= 8; ++k) if (xq >= xs[k]) i = k;
#pragma unroll
  for (int k = 1; k <= 13; ++k) if (yq >= ys[k]) j = k;
  if (i > 7) i = 7;
  if (j > 12) j = 12;
  float x0 = xs[i], x1 = xs[i + 1], y0 = ys[j], y1 = ys[j + 1];
  float tx = (xq - x0) / (x1 - x0);
  float ty = (yq - y0) / (y1 - y0);
  float f00 = tb[i * 14 + j], f01 = tb[i * 14 + j + 1];
  float f10 = tb[(i + 1) * 14 + j], f11 = tb[(i + 1) * 14 + j + 1];
  return f00 * (1 - tx) * (1 - ty) + f10 * tx * (1 - ty) +
         f01 * (1 - tx) * ty + f11 * tx * ty;
}

// ---------- kernel 1: moments of u (4 means + 10 second moments) ----------
__global__ void stats1_kernel(const float* __restrict__ x,
                              const float* __restrict__ tsg,
                              const float* __restrict__ teg,
                              const float* __restrict__ tbg,
                              float* __restrict__ mom) {
  __shared__ float ts[9], te[14], tb[126], bacc[14];
  int t = threadIdx.x;
  if (t < 9) ts[t] = tsg[t];
  if (t < 14) { te[t] = teg[t]; bacc[t] = 0.f; }
  if (t < 126) tb[t] = tbg[t];
  __syncthreads();
  const float* xr = x + (size_t)(blockIdx.x * 256 + t) * 15;
  float amb = xr[1], inc = xr[8];
  float u0 = inter2d_d(ts, te, tb, xr[2], amb) - inc;
  float u1 = inter2d_d(ts, te, tb, xr[3], amb) - inc;
  float u2 = amb, u3 = xr[9] - xr[10];
  float v[14] = {u0, u1, u2, u3,
                 u0 * u0, u0 * u1, u0 * u2, u0 * u3,
                 u1 * u1, u1 * u2, u1 * u3,
                 u2 * u2, u2 * u3, u3 * u3};
#pragma unroll
  for (int i = 0; i < 14; ++i) {
    float s = v[i];
    s += __shfl_xor(s, 32); s += __shfl_xor(s, 16); s += __shfl_xor(s, 8);
    s += __shfl_xor(s, 4);  s += __shfl_xor(s, 2);  s += __shfl_xor(s, 1);
    v[i] = s;
  }
  if ((t & 63) == 0)
    for (int i = 0; i < 14; ++i) atomicAdd(&bacc[i], v[i]);
  __syncthreads();
  if (t < 14) atomicAdd(&mom[t], bacc[t]);
}

// ---------- kernel 2: fold BN1 into A1t[512][4], c1[512] ----------
__global__ void prep1_kernel(const float* __restrict__ mom,
                             const float* __restrict__ w1,
                             const float* __restrict__ g1,
                             const float* __restrict__ be1,
                             float* __restrict__ A1t, float* __restrict__ c1,
                             float invB) {
  int j = threadIdx.x;  // 512
  float m0 = mom[0] * invB, m1 = mom[1] * invB, m2 = mom[2] * invB, m3 = mom[3] * invB;
  float C00 = mom[4]  * invB - m0 * m0, C01 = mom[5]  * invB - m0 * m1;
  float C02 = mom[6]  * invB - m0 * m2, C03 = mom[7]  * invB - m0 * m3;
  float C11 = mom[8]  * invB - m1 * m1, C12 = mom[9]  * invB - m1 * m2;
  float C13 = mom[10] * invB - m1 * m3, C22 = mom[11] * invB - m2 * m2;
  float C23 = mom[12] * invB - m2 * m3, C33 = mom[13] * invB - m3 * m3;
  float a = w1[j], b = w1[512 + j], c = w1[1024 + j], d = w1[1536 + j];
  float var = a * a * C00 + b * b * C11 + c * c * C22 + d * d * C33 +
              2.f * (a * b * C01 + a * c * C02 + a * d * C03 +
                     b * c * C12 + b * d * C13 + c * d * C23);
  float s1 = g1[j] * rsqrtf(fmaxf(var, 0.f) + 1e-5f);
  A1t[j * 4 + 0] = a * s1; A1t[j * 4 + 1] = b * s1;
  A1t[j * 4 + 2] = c * s1; A1t[j * 4 + 3] = d * s1;
  c1[j] = be1[j] - (m0 * a + m1 * b + m2 * c + m3 * d) * s1;  // b1 cancels in BN
}

// ---------- kernel 3: w2 -> bf16, frag-contiguous image ----------
// chunk index q = (it*4 + c)*512 + n ; content = w2[it*32 + c*8 + e][n], e=0..7
__global__ void transpose_w2(const float* __restrict__ w2,
                             unsigned char* __restrict__ w2ts) {
  int q = blockIdx.x * 256 + threadIdx.x;  // 0..32767
  int n = q & 511;
  int kb = (q >> 9) * 8;
  u32 pk[4];
#pragma unroll
  for (int e = 0; e < 8; e += 2) {
    u16 a = f2bf(w2[(size_t)(kb + e) * 512 + n]);
    u16 b = f2bf(w2[(size_t)(kb + e + 1) * 512 + n]);
    pk[e >> 1] = (u32)a | ((u32)b << 16);
  }
  *(uint4*)(w2ts + (size_t)q * 16) = make_uint4(pk[0], pk[1], pk[2], pk[3]);
}

// ---------- kernel 5: fold BN2 into s2,c2 (b2 cancels exactly) ----------
__global__ void prep2_kernel(const float* __restrict__ stat2,
                             const float* __restrict__ g2,
                             const float* __restrict__ be2,
                             float* __restrict__ s2, float* __restrict__ c2,
                             float invB) {
  int j = threadIdx.x;
  float mu = stat2[j] * invB;
  float ex2 = stat2[512 + j] * invB;
  float var = fmaxf(ex2 - mu * mu, 0.f);
  float s = g2[j] * rsqrtf(var + 1e-5f);
  s2[j] = s; c2[j] = be2[j] - mu * s;
}

// ---------- kernels 4 & 6: fused t1 + GEMM(t1 @ w2) ----------
// Block: 512 threads = 8 waves; M=128 rows, N=512 cols; wave tile 64x128.
// A (t1) in LDS frag-chunk-major; B direct L2->VGPR, reg-double-buffered.
// K-stagger: block starts at iteration (blockIdx.x & 15) to spread L2-bank load.
template <int EPI>
__global__ __launch_bounds__(512) void gemm_fused(
    const float* __restrict__ x, const float* __restrict__ tsg,
    const float* __restrict__ teg, const float* __restrict__ tbg,
    const float* __restrict__ A1g, const float* __restrict__ c1g,
    const unsigned char* __restrict__ w2ts, float* __restrict__ stat2,
    const float* __restrict__ s2g, const float* __restrict__ c2g,
    const float* __restrict__ w3g, const float* __restrict__ b3g,
    float* __restrict__ out) {
  __shared__ __align__(16) unsigned char sm_t1[131072];  // chunk (c*128+row)*16, c=0..63
  __shared__ __align__(16) float sm_A1t[2048];           // [j][4]
  __shared__ float sm_c1[512];
  __shared__ __align__(16) float sm_u[128][4];           // reused as pr[128][4] in EPI=1
  __shared__ float sm_ts[9], sm_te[14], sm_tb[126];

  const int t = threadIdx.x;
  const int w = t >> 6, l = t & 63;
  const int mg = w & 1, ng = w >> 1;   // rows mg*64.., cols ng*128..
  const int hi = l >> 5, ln = l & 31;
  const int r0 = blockIdx.x * 128;
  const int ph = blockIdx.x & 15;

  // B frag pointer (uint4 units): frag(j,s,nt) = bpt[j*2048 + s*1024 + nt*32]
  const uint4* bpt = (const uint4*)w2ts + (size_t)hi * 512 + ng * 128 + ln;

  uint4 b0[8], b1[8];
  auto loadB = [&](uint4* dst, int j) {
    const uint4* src = bpt + (size_t)j * 2048;
#pragma unroll
    for (int s = 0; s < 2; ++s)
#pragma unroll
      for (int nt = 0; nt < 4; ++nt) dst[s * 4 + nt] = src[s * 1024 + nt * 32];
  };
  loadB(b0, ph);  // iter-0 slab lands during the prologue

  // stage constants
  if (t < 9) sm_ts[t] = tsg[t];
  if (t < 14) sm_te[t] = teg[t];
  if (t < 126) sm_tb[t] = tbg[t];
  ((float4*)sm_A1t)[t] = ((const float4*)A1g)[t];
  sm_c1[t & 511] = c1g[t & 511];
  __syncthreads();

  if (t < 128) {
    const float* xr = x + (size_t)(r0 + t) * 15;
    float amb = xr[1], inc = xr[8];
    sm_u[t][0] = inter2d_d(sm_ts, sm_te, sm_tb, xr[2], amb) - inc;
    sm_u[t][1] = inter2d_d(sm_ts, sm_te, sm_tb, xr[3], amb) - inc;
    sm_u[t][2] = amb;
    sm_u[t][3] = xr[9] - xr[10];
  }
  __syncthreads();

  // prologue: t1 = tanh(u@A1 + c1) bf16 into frag layout.
  // thread t: row = t&127, chunks c = (t>>7)*16 + ic (wave-uniform c)
  {
    const int row = t & 127, g = t >> 7;
    float4 uv = *(const float4*)&sm_u[row][0];
#pragma unroll
    for (int ic = 0; ic < 16; ++ic) {
      int c = g * 16 + ic;
      u32 pk[4];
#pragma unroll
      for (int jj = 0; jj < 8; jj += 2) {
        int j0 = c * 8 + jj;
        float4 a0 = *(const float4*)&sm_A1t[j0 * 4];
        float4 a1 = *(const float4*)&sm_A1t[j0 * 4 + 4];
        float h0 = sm_c1[j0] + uv.x * a0.x + uv.y * a0.y + uv.z * a0.z + uv.w * a0.w;
        float h1 = sm_c1[j0 + 1] + uv.x * a1.x + uv.y * a1.y + uv.z * a1.z + uv.w * a1.w;
        pk[jj >> 1] = pack2bf(fast_tanh(h0), fast_tanh(h1));
      }
      *(uint4*)(sm_t1 + ((size_t)c * 128 + row) * 16) = make_uint4(pk[0], pk[1], pk[2], pk[3]);
    }
  }
  __syncthreads();

  f32x16 acc[8];  // [mf*4+nt]
#pragma unroll
  for (int i = 0; i < 8; ++i)
#pragma unroll
    for (int k = 0; k < 16; ++k) acc[i][k] = 0.0f;

  // A base: rows mg*64 + {0,32} + ln ; chunk c = j*4 + 2s + hi
  const unsigned char* at = sm_t1 + ((size_t)hi * 2048 + (mg * 64 + ln) * 16);

  auto step = [&](int j, const uint4* bbuf) {
#pragma unroll
    for (int s = 0; s < 2; ++s) {
      const unsigned char* ab = at + (size_t)j * 8192 + s * 4096;
      bf16x8 a0 = *(const bf16x8*)(ab);
      bf16x8 a1 = *(const bf16x8*)(ab + 512);  // +32 rows
#pragma unroll
      for (int nt = 0; nt < 4; ++nt) {
        bf16x8 bv = __builtin_bit_cast(bf16x8, bbuf[s * 4 + nt]);
        acc[nt]     = __builtin_amdgcn_mfma_f32_32x32x16_bf16(a0, bv, acc[nt], 0, 0, 0);
        acc[4 + nt] = __builtin_amdgcn_mfma_f32_32x32x16_bf16(a1, bv, acc[4 + nt], 0, 0, 0);
      }
    }
  };

  // K loop: 16 staggered iters, manually 2x unrolled, no barriers.
#pragma unroll 1
  for (int i2 = 0; i2 < 8; ++i2) {
    int i = i2 * 2;
    loadB(b1, (i + 1 + ph) & 15);
    step((i + ph) & 15, b0);
    if (i2 < 7) loadB(b0, (i + 2 + ph) & 15);
    step((i + 1 + ph) & 15, b1);
  }

  // C/D layout (32x32x16): col = lane&31, row_in_tile = (k&3) + 8*(k>>2) + 4*hi
  if (EPI == 0) {
#pragma unroll
    for (int nt = 0; nt < 4; ++nt) {
      float s = 0.f, q = 0.f;
#pragma unroll
      for (int mf = 0; mf < 2; ++mf)
#pragma unroll
        for (int k = 0; k < 16; ++k) {
          float v = acc[mf * 4 + nt][k];
          s += v; q += v * v;
        }
      s += __shfl_xor(s, 32); q += __shfl_xor(q, 32);
      if (hi == 0) {
        int col = ng * 128 + nt * 32 + ln;
        atomicAdd(&stat2[col], s);
        atomicAdd(&stat2[512 + col], q);
      }
    }
  } else {
    float sv[4], cv[4], wv[4];
#pragma unroll
    for (int nt = 0; nt < 4; ++nt) {
      int col = ng * 128 + nt * 32 + ln;
      sv[nt] = s2g[col]; cv[nt] = c2g[col]; wv[nt] = w3g[col];
    }
    float rs[2][16];
#pragma unroll
    for (int mf = 0; mf < 2; ++mf)
#pragma unroll
      for (int k = 0; k < 16; ++k) rs[mf][k] = 0.f;
#pragma unroll
    for (int nt = 0; nt < 4; ++nt)
#pragma unroll
      for (int mf = 0; mf < 2; ++mf)
#pragma unroll
        for (int k = 0; k < 16; ++k)
          rs[mf][k] += fast_tanh(acc[mf * 4 + nt][k] * sv[nt] + cv[nt]) * wv[nt];
    float* pr = &sm_u[0][0];  // reuse as [128 rows][4 ng]
#pragma unroll
    for (int mf = 0; mf < 2; ++mf)
#pragma unroll
      for (int k = 0; k < 16; ++k) {
        float v = rs[mf][k];
        v += __shfl_xor(v, 1); v += __shfl_xor(v, 2); v += __shfl_xor(v, 4);
        v += __shfl_xor(v, 8); v += __shfl_xor(v, 16);
        if (ln == 0) {
          int row = mg * 64 + mf * 32 + (k & 3) + 8 * (k >> 2) + 4 * hi;
          pr[row * 4 + ng] = v;
        }
      }
    __syncthreads();
    if (t < 128)
      out[r0 + t] = pr[t * 4] + pr[t * 4 + 1] + pr[t * 4 + 2] + pr[t * 4 + 3] + b3g[0];
  }
}

// ---------- launcher ----------
extern "C" void kernel_launch(void* const* d_in, const int* in_sizes, int n_in,
                              void* d_out, int out_size, void* d_ws, size_t ws_size,
                              hipStream_t stream) {
  const float* x   = (const float*)d_in[0];
  const float* ts  = (const float*)d_in[1];
  const float* te  = (const float*)d_in[2];
  const float* tab = (const float*)d_in[3];
  const float* w1  = (const float*)d_in[4];
  const float* g1  = (const float*)d_in[6];
  const float* be1 = (const float*)d_in[7];
  const float* w2  = (const float*)d_in[8];
  const float* g2  = (const float*)d_in[10];
  const float* be2 = (const float*)d_in[11];
  const float* w3  = (const float*)d_in[12];
  const float* b3  = (const float*)d_in[13];
  float* out = (float*)d_out;
  char* ws = (char*)d_ws;

  if (ws_size < (size_t)(32768 + 524288)) return;

  int Bn = in_sizes[0] / 15;  // 262144
  float invB = 1.0f / (float)Bn;

  float* mom   = (float*)(ws + 0);      // 14 f32 (zeroed)
  float* stat2 = (float*)(ws + 64);     // 1024 f32 (zeroed)
  float* A1    = (float*)(ws + 4160);   // 2048 f32 (A1t[512][4])
  float* c1    = (float*)(ws + 12352);  // 512 f32
  float* s2    = (float*)(ws + 14400);  // 512 f32
  float* c2    = (float*)(ws + 16448);  // 512 f32
  unsigned char* w2ts = (unsigned char*)(ws + 32768);  // 512 KB bf16 image

  (void)hipMemsetAsync(ws, 0, 4160, stream);
  stats1_kernel<<<Bn / 256, 256, 0, stream>>>(x, ts, te, tab, mom);
  prep1_kernel<<<1, 512, 0, stream>>>(mom, w1, g1, be1, A1, c1, invB);
  transpose_w2<<<128, 256, 0, stream>>>(w2, w2ts);
  gemm_fused<0><<<Bn / 128, 512, 0, stream>>>(x, ts, te, tab, A1, c1, w2ts, stat2,
                                              nullptr, nullptr, nullptr, nullptr, nullptr);
  prep2_kernel<<<1, 512, 0, stream>>>(stat2, g2, be2, s2, c2, invB);
  gemm_fused<1><<<Bn / 128, 512, 0, stream>>>(x, ts, te, tab, A1, c1, w2ts, stat2,
                                              s2, c2, w3, b3, out);
}

// Round 6
// 500.049 us; speedup vs baseline: 1.1497x; 1.1497x over previous
//
#include <hip/hip_runtime.h>

typedef unsigned int u32;
typedef unsigned short u16;
typedef __bf16 bf16x8 __attribute__((ext_vector_type(8)));
typedef float f32x16 __attribute__((ext_vector_type(16)));
typedef u32 u32x4 __attribute__((ext_vector_type(4)));

// ---------- helpers ----------
__device__ __forceinline__ u16 f2bf(float f) {
  u32 u = __float_as_uint(f);
  u32 r = (u + 0x7FFFu + ((u >> 16) & 1u)) >> 16;
  return (u16)r;
}
__device__ __forceinline__ float bf2f(u16 h) {
  return __uint_as_float((u32)h << 16);
}
__device__ __forceinline__ u32 pack2bf(float a, float b) {
  return (u32)f2bf(a) | ((u32)f2bf(b) << 16);
}
__device__ __forceinline__ float fast_tanh(float x) {
  float e = __expf(2.0f * x);
  return 1.0f - 2.0f * __builtin_amdgcn_rcpf(e + 1.0f);
}

// bilinear interp matching jnp.searchsorted(side='right')-1 with clamping
__device__ __forceinline__ float inter2d_d(const float* xs, const float* ys,
                                           const float* tb, float xq, float yq) {
  xq = fminf(fmaxf(xq, xs[0]), xs[8]);
  yq = fminf(fmaxf(yq, ys[0]), ys[13]);
  int i = 0, j = 0;
#pragma unroll
  for (int k = 1; k <= 8; ++k) if (xq >= xs[k]) i = k;
#pragma unroll
  for (int k = 1; k <= 13; ++k) if (yq >= ys[k]) j = k;
  if (i > 7) i = 7;
  if (j > 12) j = 12;
  float x0 = xs[i], x1 = xs[i + 1], y0 = ys[j], y1 = ys[j + 1];
  float tx = (xq - x0) / (x1 - x0);
  float ty = (yq - y0) / (y1 - y0);
  float f00 = tb[i * 14 + j], f01 = tb[i * 14 + j + 1];
  float f10 = tb[(i + 1) * 14 + j], f11 = tb[(i + 1) * 14 + j + 1];
  return f00 * (1 - tx) * (1 - ty) + f10 * tx * (1 - ty) +
         f01 * (1 - tx) * ty + f11 * tx * ty;
}

// ---------- kernel 1: moments of u (4 means + 10 second moments) ----------
__global__ void stats1_kernel(const float* __restrict__ x,
                              const float* __restrict__ tsg,
                              const float* __restrict__ teg,
                              const float* __restrict__ tbg,
                              float* __restrict__ mom) {
  __shared__ float ts[9], te[14], tb[126], bacc[14];
  int t = threadIdx.x;
  if (t < 9) ts[t] = tsg[t];
  if (t < 14) { te[t] = teg[t]; bacc[t] = 0.f; }
  if (t < 126) tb[t] = tbg[t];
  __syncthreads();
  const float* xr = x + (size_t)(blockIdx.x * 256 + t) * 15;
  float amb = xr[1], inc = xr[8];
  float u0 = inter2d_d(ts, te, tb, xr[2], amb) - inc;
  float u1 = inter2d_d(ts, te, tb, xr[3], amb) - inc;
  float u2 = amb, u3 = xr[9] - xr[10];
  float v[14] = {u0, u1, u2, u3,
                 u0 * u0, u0 * u1, u0 * u2, u0 * u3,
                 u1 * u1, u1 * u2, u1 * u3,
                 u2 * u2, u2 * u3, u3 * u3};
#pragma unroll
  for (int i = 0; i < 14; ++i) {
    float s = v[i];
    s += __shfl_xor(s, 32); s += __shfl_xor(s, 16); s += __shfl_xor(s, 8);
    s += __shfl_xor(s, 4);  s += __shfl_xor(s, 2);  s += __shfl_xor(s, 1);
    v[i] = s;
  }
  if ((t & 63) == 0)
    for (int i = 0; i < 14; ++i) atomicAdd(&bacc[i], v[i]);
  __syncthreads();
  if (t < 14) atomicAdd(&mom[t], bacc[t]);
}

// ---------- kernel 2: fold BN1 into the layer-1 MFMA A-frag image ----------
// Error-compensated: per j two 16B frags (hi=0/1):
//  hi0: [bf(a0..a3), c1_hi, da0, da1, da2]   (da = bf(a - bf(a)))
//  hi1: [bf(a0..a3), c1_lo, da3, 0, 0]
// Paired with u-frags carrying [bf(u),1,bf(u0..2)] / [du,1,bf(u3),0,0]:
// h1 = sum a_i*u_i + c1 accurate to ~2^-16 relative.  b1 cancels in train-BN.
__global__ void prep1_kernel(const float* __restrict__ mom,
                             const float* __restrict__ w1,
                             const float* __restrict__ g1,
                             const float* __restrict__ be1,
                             unsigned char* __restrict__ a1img, float invB) {
  int j = threadIdx.x;  // 512
  float m0 = mom[0] * invB, m1 = mom[1] * invB, m2 = mom[2] * invB, m3 = mom[3] * invB;
  float C00 = mom[4]  * invB - m0 * m0, C01 = mom[5]  * invB - m0 * m1;
  float C02 = mom[6]  * invB - m0 * m2, C03 = mom[7]  * invB - m0 * m3;
  float C11 = mom[8]  * invB - m1 * m1, C12 = mom[9]  * invB - m1 * m2;
  float C13 = mom[10] * invB - m1 * m3, C22 = mom[11] * invB - m2 * m2;
  float C23 = mom[12] * invB - m2 * m3, C33 = mom[13] * invB - m3 * m3;
  float a = w1[j], b = w1[512 + j], c = w1[1024 + j], d = w1[1536 + j];
  float var = a * a * C00 + b * b * C11 + c * c * C22 + d * d * C33 +
              2.f * (a * b * C01 + a * c * C02 + a * d * C03 +
                     b * c * C12 + b * d * C13 + c * d * C23);
  float s1 = g1[j] * rsqrtf(fmaxf(var, 0.f) + 1e-5f);
  float a0 = a * s1, a1 = b * s1, a2 = c * s1, a3 = d * s1;
  float c1j = be1[j] - (m0 * a + m1 * b + m2 * c + m3 * d) * s1;
  u16 ba0 = f2bf(a0), ba1 = f2bf(a1), ba2 = f2bf(a2), ba3 = f2bf(a3);
  u16 da0 = f2bf(a0 - bf2f(ba0)), da1 = f2bf(a1 - bf2f(ba1));
  u16 da2 = f2bf(a2 - bf2f(ba2)), da3 = f2bf(a3 - bf2f(ba3));
  u16 c1h = f2bf(c1j);
  u16 c1l = f2bf(c1j - bf2f(c1h));
  u32 p01 = (u32)ba0 | ((u32)ba1 << 16);
  u32 p23 = (u32)ba2 | ((u32)ba3 << 16);
  uint4* img = (uint4*)a1img;
  img[j * 2]     = make_uint4(p01, p23, (u32)c1h | ((u32)da0 << 16),
                              (u32)da1 | ((u32)da2 << 16));
  img[j * 2 + 1] = make_uint4(p01, p23, (u32)c1l | ((u32)da3 << 16), 0u);
}

// ---------- kernel 3: w2 -> bf16, frag-contiguous image ----------
// chunk index q = G*512 + n (G = global K-octet 0..63); content = w2[G*8+e][n]
__global__ void transpose_w2(const float* __restrict__ w2,
                             unsigned char* __restrict__ w2ts) {
  int q = blockIdx.x * 256 + threadIdx.x;  // 0..32767
  int n = q & 511;
  int kb = (q >> 9) * 8;
  u32 pk[4];
#pragma unroll
  for (int e = 0; e < 8; e += 2) {
    u16 a = f2bf(w2[(size_t)(kb + e) * 512 + n]);
    u16 b = f2bf(w2[(size_t)(kb + e + 1) * 512 + n]);
    pk[e >> 1] = (u32)a | ((u32)b << 16);
  }
  *(uint4*)(w2ts + (size_t)q * 16) = make_uint4(pk[0], pk[1], pk[2], pk[3]);
}

// ---------- kernel 5: fold BN2 into s2,c2 (b2 cancels exactly) ----------
__global__ void prep2_kernel(const float* __restrict__ stat2,
                             const float* __restrict__ g2,
                             const float* __restrict__ be2,
                             float* __restrict__ s2, float* __restrict__ c2,
                             float invB) {
  int j = threadIdx.x;
  float mu = stat2[j] * invB;
  float ex2 = stat2[512 + j] * invB;
  float var = fmaxf(ex2 - mu * mu, 0.f);
  float s = g2[j] * rsqrtf(var + 1e-5f);
  s2[j] = s; c2[j] = be2[j] - mu * s;
}

// ---------- kernels 4 & 6: fused t1 + GEMM(t1 @ w2), pipelined slabs ----------
// 512 thr = 8 waves; block M=128 rows, N=512 cols; wave tile 128x64 (4mf x 2nf,
// no B duplication). t1 produced in 128-K slabs via layer-1 MFMA, double-buffered
// in LDS; production of slab s+1 overlaps main MFMA of slab s. B direct L2->VGPR.
template <int EPI>
__global__ __launch_bounds__(512, 2) void gemm_fused(
    const float* __restrict__ x, const float* __restrict__ tsg,
    const float* __restrict__ teg, const float* __restrict__ tbg,
    const unsigned char* __restrict__ a1img,
    const unsigned char* __restrict__ w2ts, float* __restrict__ stat2,
    const float* __restrict__ s2g, const float* __restrict__ c2g,
    const float* __restrict__ w3g, const float* __restrict__ b3g,
    float* __restrict__ out) {
  __shared__ __align__(16) unsigned char sm_buf[2][32768];  // t1 slabs, chunk-major
  __shared__ __align__(16) float sm_u[128][4];
  __shared__ float sm_ts[9], sm_te[14], sm_tb[126];

  const int t = threadIdx.x;
  const int w = t >> 6, l = t & 63;
  const int hi = l >> 5, ln = l & 31;
  const int rt = w & 3;          // production batch row-tile (rows rt*32..)
  const int jtp = (w >> 2) * 2;  // production j-tile pair {jtp, jtp+1} (local 0..3)
  const int r0 = blockIdx.x * 128;

  if (t < 9) sm_ts[t] = tsg[t];
  if (t < 14) sm_te[t] = teg[t];
  if (t < 126) sm_tb[t] = tbg[t];
  __syncthreads();

  if (t < 128) {
    const float* xr = x + (size_t)(r0 + t) * 15;
    float amb = xr[1], inc = xr[8];
    sm_u[t][0] = inter2d_d(sm_ts, sm_te, sm_tb, xr[2], amb) - inc;
    sm_u[t][1] = inter2d_d(sm_ts, sm_te, sm_tb, xr[3], amb) - inc;
    sm_u[t][2] = amb;
    sm_u[t][3] = xr[9] - xr[10];
  }
  __syncthreads();

  // u B-frag for layer-1 MFMA: lane = batch row rt*32+ln.
  // hi0: [bf(u0..u3), 1, bf(u0), bf(u1), bf(u2)]
  // hi1: [du0..du3,   1, bf(u3), 0, 0]   (du = bf(u - bf(u)))
  bf16x8 ufrag;
  {
    float4 uv = *(const float4*)&sm_u[rt * 32 + ln][0];
    u16 b0_ = f2bf(uv.x), b1_ = f2bf(uv.y), b2_ = f2bf(uv.z), b3_ = f2bf(uv.w);
    u32x4 uq;
    if (hi == 0) {
      uq[0] = (u32)b0_ | ((u32)b1_ << 16);
      uq[1] = (u32)b2_ | ((u32)b3_ << 16);
      uq[2] = 0x00003F80u | ((u32)b0_ << 16);
      uq[3] = (u32)b1_ | ((u32)b2_ << 16);
    } else {
      u16 d0 = f2bf(uv.x - bf2f(b0_)), d1 = f2bf(uv.y - bf2f(b1_));
      u16 d2 = f2bf(uv.z - bf2f(b2_)), d3 = f2bf(uv.w - bf2f(b3_));
      uq[0] = (u32)d0 | ((u32)d1 << 16);
      uq[1] = (u32)d2 | ((u32)d3 << 16);
      uq[2] = 0x00003F80u | ((u32)b3_ << 16);
      uq[3] = 0u;
    }
    ufrag = __builtin_bit_cast(bf16x8, uq);
  }

  // produce t1 slab sl into sm_buf[sl&1]: 2 j-tiles per wave, 1 MFMA each,
  // tanh + bf16 pack, j-quads -> ds_write_b64 straight into A-frag layout.
  auto produce = [&](int sl) {
    unsigned char* dst = sm_buf[sl & 1];
#pragma unroll
    for (int i = 0; i < 2; ++i) {
      int jt = jtp + i;
      bf16x8 af = *(const bf16x8*)(a1img +
          ((size_t)(sl * 128 + jt * 32 + ln) * 32 + hi * 16));
      f32x16 z = {};
      f32x16 d = __builtin_amdgcn_mfma_f32_32x32x16_bf16(af, ufrag, z, 0, 0, 0);
#pragma unroll
      for (int q = 0; q < 4; ++q) {
        u32 plo = pack2bf(fast_tanh(d[q * 4 + 0]), fast_tanh(d[q * 4 + 1]));
        u32 phi = pack2bf(fast_tanh(d[q * 4 + 2]), fast_tanh(d[q * 4 + 3]));
        *(uint2*)(dst + ((size_t)((jt * 4 + q) * 128 + rt * 32 + ln) * 16 + hi * 8)) =
            make_uint2(plo, phi);
      }
    }
  };

  // B frag loads: global K-octet G = ks*2 + hi; cols w*64 + nf*32 + ln
  auto loadB = [&](uint4* dst, int ks) {
    const unsigned char* p = w2ts + ((size_t)(ks * 2 + hi) * 8192) +
                             (size_t)(w * 64 + ln) * 16;
    dst[0] = *(const uint4*)(p);
    dst[1] = *(const uint4*)(p + 512);
  };

  f32x16 acc[8];  // [mf*2+nf]
#pragma unroll
  for (int i = 0; i < 8; ++i)
#pragma unroll
    for (int k = 0; k < 16; ++k) acc[i][k] = 0.0f;

  produce(0);
  uint4 bb[2][2];
  loadB(bb[0], 0);
  __syncthreads();

#pragma unroll
  for (int sl = 0; sl < 4; ++sl) {
    const unsigned char* abuf = sm_buf[sl & 1];
#pragma unroll
    for (int s = 0; s < 8; ++s) {
      int ks = sl * 8 + s;
      if (ks < 31) loadB(bb[(s + 1) & 1], ks + 1);
      const unsigned char* ab = abuf + ((size_t)(2 * s + hi) * 128 + ln) * 16;
      bf16x8 a0 = *(const bf16x8*)(ab);
      bf16x8 a1 = *(const bf16x8*)(ab + 512);
      bf16x8 a2 = *(const bf16x8*)(ab + 1024);
      bf16x8 a3 = *(const bf16x8*)(ab + 1536);
#pragma unroll
      for (int nf = 0; nf < 2; ++nf) {
        bf16x8 bv = __builtin_bit_cast(bf16x8, bb[s & 1][nf]);
        acc[0 + nf] = __builtin_amdgcn_mfma_f32_32x32x16_bf16(a0, bv, acc[0 + nf], 0, 0, 0);
        acc[2 + nf] = __builtin_amdgcn_mfma_f32_32x32x16_bf16(a1, bv, acc[2 + nf], 0, 0, 0);
        acc[4 + nf] = __builtin_amdgcn_mfma_f32_32x32x16_bf16(a2, bv, acc[4 + nf], 0, 0, 0);
        acc[6 + nf] = __builtin_amdgcn_mfma_f32_32x32x16_bf16(a3, bv, acc[6 + nf], 0, 0, 0);
      }
      if (s == 0 && sl < 3) produce(sl + 1);
    }
    __syncthreads();
  }

  // C/D layout (32x32x16): col = lane&31, row_in_tile = (k&3) + 8*(k>>2) + 4*hi
  if (EPI == 0) {
#pragma unroll
    for (int nf = 0; nf < 2; ++nf) {
      float s = 0.f, q = 0.f;
#pragma unroll
      for (int mf = 0; mf < 4; ++mf)
#pragma unroll
        for (int k = 0; k < 16; ++k) {
          float v = acc[mf * 2 + nf][k];
          s += v; q += v * v;
        }
      s += __shfl_xor(s, 32); q += __shfl_xor(q, 32);
      if (hi == 0) {
        int col = w * 64 + nf * 32 + ln;
        atomicAdd(&stat2[col], s);
        atomicAdd(&stat2[512 + col], q);
      }
    }
  } else {
    float sv[2], cv[2], wv[2];
#pragma unroll
    for (int nf = 0; nf < 2; ++nf) {
      int col = w * 64 + nf * 32 + ln;
      sv[nf] = s2g[col]; cv[nf] = c2g[col]; wv[nf] = w3g[col];
    }
    float* pr = (float*)sm_buf[0];  // [128 rows][8 waves]
#pragma unroll
    for (int mf = 0; mf < 4; ++mf)
#pragma unroll
      for (int k = 0; k < 16; ++k) {
        float v = fast_tanh(acc[mf * 2 + 0][k] * sv[0] + cv[0]) * wv[0] +
                  fast_tanh(acc[mf * 2 + 1][k] * sv[1] + cv[1]) * wv[1];
        v += __shfl_xor(v, 1); v += __shfl_xor(v, 2); v += __shfl_xor(v, 4);
        v += __shfl_xor(v, 8); v += __shfl_xor(v, 16);
        if (ln == 0) {
          int row = mf * 32 + (k & 3) + 8 * (k >> 2) + 4 * hi;
          pr[row * 8 + w] = v;
        }
      }
    __syncthreads();
    if (t < 128) {
      float s = b3g[0];
#pragma unroll
      for (int i = 0; i < 8; ++i) s += pr[t * 8 + i];
      out[r0 + t] = s;
    }
  }
}

// ---------- launcher ----------
extern "C" void kernel_launch(void* const* d_in, const int* in_sizes, int n_in,
                              void* d_out, int out_size, void* d_ws, size_t ws_size,
                              hipStream_t stream) {
  const float* x   = (const float*)d_in[0];
  const float* ts  = (const float*)d_in[1];
  const float* te  = (const float*)d_in[2];
  const float* tab = (const float*)d_in[3];
  const float* w1  = (const float*)d_in[4];
  const float* g1  = (const float*)d_in[6];
  const float* be1 = (const float*)d_in[7];
  const float* w2  = (const float*)d_in[8];
  const float* g2  = (const float*)d_in[10];
  const float* be2 = (const float*)d_in[11];
  const float* w3  = (const float*)d_in[12];
  const float* b3  = (const float*)d_in[13];
  float* out = (float*)d_out;
  char* ws = (char*)d_ws;

  if (ws_size < (size_t)(32768 + 524288)) return;

  int Bn = in_sizes[0] / 15;  // 262144
  float invB = 1.0f / (float)Bn;

  float* mom   = (float*)(ws + 0);      // 14 f32 (zeroed)
  float* stat2 = (float*)(ws + 64);     // 1024 f32 (zeroed)
  unsigned char* a1img = (unsigned char*)(ws + 4160);  // 16 KB (512 j x 32B)
  float* s2    = (float*)(ws + 20544);  // 512 f32
  float* c2    = (float*)(ws + 22592);  // 512 f32
  unsigned char* w2ts = (unsigned char*)(ws + 32768);  // 512 KB bf16 image

  (void)hipMemsetAsync(ws, 0, 4160, stream);
  stats1_kernel<<<Bn / 256, 256, 0, stream>>>(x, ts, te, tab, mom);
  prep1_kernel<<<1, 512, 0, stream>>>(mom, w1, g1, be1, a1img, invB);
  transpose_w2<<<128, 256, 0, stream>>>(w2, w2ts);
  gemm_fused<0><<<Bn / 128, 512, 0, stream>>>(x, ts, te, tab, a1img, w2ts, stat2,
                                              nullptr, nullptr, nullptr, nullptr, nullptr);
  prep2_kernel<<<1, 512, 0, stream>>>(stat2, g2, be2, s2, c2, invB);
  gemm_fused<1><<<Bn / 128, 512, 0, stream>>>(x, ts, te, tab, a1img, w2ts, stat2,
                                              s2, c2, w3, b3, out);
}